// Round 19
// baseline (353.514 us; speedup 1.0000x reference)
//
#include <hip/hip_runtime.h>
#include <hip/hip_bf16.h>
#include <math.h>

#define NPTS 16384
#define DIM  128
#define NCLS 10
#define KNN  3
#define EPS  2.5e-5f      // 3-term screen bound (pass1 candidates; typical err ~1e-6)
#define MEPS 8.0e-3f      // hi-only screen bound: 2*2^-8 (bf16 7-bit mantissa) — near-tight
#define CAP  1572864      // borderline pair capacity (6 MB)
#define NSPLIT 4          // pass1 j-splits (champion config)
#define NC   24           // candidates per row = 4 splits * 6 (h-merged)
#define BLBUF 1024        // per-block LDS borderline buffer entries (4 KB)
#define FLUSHTHR 512      // flush when count exceeds this at a tile boundary

typedef float  f16v __attribute__((ext_vector_type(16)));
typedef __bf16 bf8v __attribute__((ext_vector_type(8)));

// staging address helpers: idx -> (lds slot, global byte offset within tile)
#define STADDR(k, SLOT, OFF) { int _i = tid + 256*(k); int _r = _i >> 4, _s = _i & 15; \
  SLOT = _r*16 + (_s ^ (_r & 15)); OFF = _r*256 + _s*16; }
#define STADDR512(k, SLOT, OFF) { int _i = tid + 512*(k); int _r = _i >> 4, _s = _i & 15; \
  SLOT = _r*16 + (_s ^ (_r & 15)); OFF = _r*256 + _s*16; }

// ---------------- K0: deterministic stable counting sort by class ----------------
__global__ __launch_bounds__(256) void sort_kernel(const int* __restrict__ y,
                                                   int* __restrict__ newpos,
                                                   int* __restrict__ y_new,
                                                   int* __restrict__ cls_start) {
  __shared__ int cnt[256 * NCLS];
  __shared__ int base[NCLS + 1];
  int t = threadIdx.x;
#pragma unroll
  for (int c = 0; c < NCLS; ++c) cnt[t * NCLS + c] = 0;
  for (int k = 0; k < 64; ++k) cnt[t * NCLS + y[t * 64 + k]]++;
  __syncthreads();
  if (t < NCLS) {
    int run = 0;
    for (int b = 0; b < 256; ++b) { int v = cnt[b * NCLS + t]; cnt[b * NCLS + t] = run; run += v; }
    base[t + 1] = run;
  }
  __syncthreads();
  if (t == 0) {
    base[0] = 0;
    for (int c = 1; c <= NCLS; ++c) base[c] += base[c - 1];
    for (int c = 0; c <= NCLS; ++c) cls_start[c] = base[c];
  }
  __syncthreads();
  for (int k = 0; k < 64; ++k) {
    int i = t * 64 + k;
    int c = y[i];
    int p = base[c] + cnt[t * NCLS + c]++;
    newpos[i] = p;
    y_new[p] = c;
  }
}

// ---------------- K1: normalize + bf16 hi/lo split, scattered to sorted order ----------
__global__ __launch_bounds__(256) void prep_kernel(const float* __restrict__ X,
                                                   const int* __restrict__ newpos,
                                                   float* __restrict__ Xn,
                                                   ushort* __restrict__ Hi,
                                                   ushort* __restrict__ Lo) {
  int row  = blockIdx.x * 4 + (threadIdx.x >> 6);
  int lane = threadIdx.x & 63;
  const float* xr = X + (size_t)row * DIM;
  float a = xr[lane], b = xr[lane + 64];
  float ss = a * a + b * b;
#pragma unroll
  for (int off = 32; off > 0; off >>= 1) ss += __shfl_xor(ss, off);
  float nrm = fmaxf(sqrtf(ss), 1e-8f);
  float an = a / nrm, bn = b / nrm;
  size_t np = (size_t)newpos[row];
  Xn[np * DIM + lane]      = an;
  Xn[np * DIM + lane + 64] = bn;
  __hip_bfloat16 ha = __float2bfloat16(an);
  __hip_bfloat16 hb = __float2bfloat16(bn);
  __hip_bfloat16 la = __float2bfloat16(an - __bfloat162float(ha));
  __hip_bfloat16 lb = __float2bfloat16(bn - __bfloat162float(hb));
  Hi[np * DIM + lane]      = *(ushort*)&ha;
  Hi[np * DIM + lane + 64] = *(ushort*)&hb;
  Lo[np * DIM + lane]      = *(ushort*)&la;
  Lo[np * DIM + lane + 64] = *(ushort*)&lb;
}

// ---------------- shared MFMA helper (identical dot path in both passes) -------------
__device__ __forceinline__ f16v tile_mfma(const float4* BH, const float4* BL,
                                          const bf8v bhi[8], const bf8v blo[8],
                                          int lrow, int h) {
  f16v acc = {0,0,0,0,0,0,0,0,0,0,0,0,0,0,0,0};
  int rswz = lrow & 15;
  bf8v ah[8], al[8];
#pragma unroll
  for (int c = 0; c < 8; ++c) ah[c] = ((const bf8v*)BH)[lrow * 16 + ((c * 2 + h) ^ rswz)];
#pragma unroll
  for (int c = 0; c < 8; ++c)
    acc = __builtin_amdgcn_mfma_f32_32x32x16_bf16(ah[c], bhi[c], acc, 0, 0, 0);
#pragma unroll
  for (int c = 0; c < 8; ++c) al[c] = ((const bf8v*)BL)[lrow * 16 + ((c * 2 + h) ^ rswz)];
#pragma unroll
  for (int c = 0; c < 8; ++c)
    acc = __builtin_amdgcn_mfma_f32_32x32x16_bf16(al[c], bhi[c], acc, 0, 0, 0);
#pragma unroll
  for (int c = 0; c < 8; ++c)
    acc = __builtin_amdgcn_mfma_f32_32x32x16_bf16(ah[c], blo[c], acc, 0, 0, 0);
  return acc;
}

// ---------------- K2: pass 1 — champion pipeline + deferred-mask scan ----------------
__global__ __launch_bounds__(256) void pass1_kernel(const ushort* __restrict__ Hi,
                                                    const ushort* __restrict__ Lo,
                                                    const int* __restrict__ y_new,
                                                    const int* __restrict__ cls_start,
                                                    int* __restrict__ candj) {
  __shared__ float4 BH[2][64 * 16];            // 32 KB double buffer (hi)
  __shared__ float4 BL[2][64 * 16];            // 32 KB double buffer (lo)
  int tid = threadIdx.x;
  int wave = tid >> 6, lane = tid & 63;
  int col = lane & 31, h = lane >> 5;
  int rb = blockIdx.x >> 2, s = blockIdx.x & 3;
  int irow = rb * 128 + wave * 32 + col;
  int myc = y_new[irow];
  int cs = cls_start[myc], ce = cls_start[myc + 1];
  int c_first = y_new[rb * 128];
  int c_last  = y_new[rb * 128 + 127];
  int jlo = cls_start[c_first], jhi = cls_start[c_last + 1];
  int T0 = jlo >> 6, T1 = (jhi + 63) >> 6;
  int TS0 = T0 + ((T1 - T0) * s) / NSPLIT;
  int TS1 = T0 + ((T1 - T0) * (s + 1)) / NSPLIT;

  bf8v bhi[8], blo[8];
#pragma unroll
  for (int c = 0; c < 8; ++c) {
    bhi[c] = *(const bf8v*)(Hi + (size_t)irow * DIM + c * 16 + h * 8);
    blo[c] = *(const bf8v*)(Lo + (size_t)irow * DIM + c * 16 + h * 8);
  }

  int sl0, sl1, sl2, sl3, of0, of1, of2, of3;
  STADDR(0, sl0, of0) STADDR(1, sl1, of1) STADDR(2, sl2, of2) STADDR(3, sl3, of3)

  float t0=-3e38f,t1=-3e38f,t2=-3e38f,t3=-3e38f,t4=-3e38f,t5=-3e38f;
  int   j0=-1,j1=-1,j2=-1,j3=-1,j4=-1,j5=-1;

#define INS(v, jj) do { float _pv = (v); int _pj = (jj); \
  if (_pv > t5) { t5 = _pv; j5 = _pj; \
    if (t5 > t4) { float _v=t4;t4=t5;t5=_v; int _j=j4;j4=j5;j5=_j; } \
    if (t4 > t3) { float _v=t3;t3=t4;t4=_v; int _j=j3;j3=j4;j4=_j; } \
    if (t3 > t2) { float _v=t2;t2=t3;t3=_v; int _j=j2;j2=j3;j3=_j; } \
    if (t2 > t1) { float _v=t1;t1=t2;t2=_v; int _j=j1;j1=j2;j2=_j; } \
    if (t1 > t0) { float _v=t0;t0=t1;t1=_v; int _j=j0;j0=j1;j1=_j; } } } while(0)

  {                                            // prologue: stage first tile into buf0
    const char* hb = (const char*)Hi + (size_t)TS0 * 16384;
    const char* lb = (const char*)Lo + (size_t)TS0 * 16384;
    BH[0][sl0] = *(const float4*)(hb + of0); BH[0][sl1] = *(const float4*)(hb + of1);
    BH[0][sl2] = *(const float4*)(hb + of2); BH[0][sl3] = *(const float4*)(hb + of3);
    BL[0][sl0] = *(const float4*)(lb + of0); BL[0][sl1] = *(const float4*)(lb + of1);
    BL[0][sl2] = *(const float4*)(lb + of2); BL[0][sl3] = *(const float4*)(lb + of3);
  }
  __syncthreads();
  int cur = 0;

  for (int t = TS0; t < TS1; ++t) {
    int tp = (t + 1 < TS1) ? t + 1 : t;        // unconditional clamped prefetch (no spill)
    const char* hb = (const char*)Hi + (size_t)tp * 16384;
    const char* lb = (const char*)Lo + (size_t)tp * 16384;
    float4 rh0 = *(const float4*)(hb + of0), rh1 = *(const float4*)(hb + of1);
    float4 rh2 = *(const float4*)(hb + of2), rh3 = *(const float4*)(hb + of3);
    float4 rl0 = *(const float4*)(lb + of0), rl1 = *(const float4*)(lb + of1);
    float4 rl2 = *(const float4*)(lb + of2), rl3 = *(const float4*)(lb + of3);
#pragma unroll
    for (int js2 = 0; js2 < 2; ++js2) {
      int jbase = t * 64 + js2 * 32;
      f16v acc = tile_mfma(BH[cur], BL[cur], bhi, blo, js2 * 32 + col, h);
      // dd is wave-uniform: this wave's 32 i-rows == this 32-j subtile
      bool dd = (irow >= jbase) && (irow < jbase + 32);
      if (__builtin_expect(dd, 0)) {           // rare: subtile containing self — full path
#pragma unroll
        for (int r = 0; r < 16; ++r) {
          int jrow = (r & 3) + 8 * (r >> 2) + 4 * h;
          int jg = jbase + jrow;
          float dot = acc[r];
          if (jg == irow) dot = 2.0f;          // self sentinel: guaranteed kept
          bool ok = (jg >= cs) && (jg < ce);
          if (ok) INS(dot, jg);
        }
      } else {
        // deferred-mask scan: 3 ops/elem common path; drain in ascending-r order
        // (identical insert set: mask only removes elems <= start t5, which also
        //  fail at their processing time since t5 is monotone non-decreasing)
        uint mask = 0;
#pragma unroll
        for (int r = 0; r < 16; ++r)
          mask |= (acc[r] > t5 ? 1u : 0u) << r;
        while (mask) {
          int r = __ffs(mask) - 1;
          mask &= mask - 1;
          int jrow = (r & 3) + 8 * (r >> 2) + 4 * h;
          int jg = jbase + jrow;
          float dot = acc[r];
          if (jg >= cs && jg < ce) INS(dot, jg);  // INS rechecks > current t5
        }
      }
    }
    // write prefetched tile into the other buffer (vmcnt wait lands here, post-compute)
    BH[cur ^ 1][sl0] = rh0; BH[cur ^ 1][sl1] = rh1;
    BH[cur ^ 1][sl2] = rh2; BH[cur ^ 1][sl3] = rh3;
    BL[cur ^ 1][sl0] = rl0; BL[cur ^ 1][sl1] = rl1;
    BL[cur ^ 1][sl2] = rl2; BL[cur ^ 1][sl3] = rl3;
    __syncthreads();                           // single barrier per tile
    cur ^= 1;
  }

  // h-merge: exchange lists across lane^32 (same i-row, disjoint j-subsets)
  float m0 = __shfl_xor(t0, 32), m1 = __shfl_xor(t1, 32), m2 = __shfl_xor(t2, 32);
  float m3 = __shfl_xor(t3, 32), m4 = __shfl_xor(t4, 32), m5 = __shfl_xor(t5, 32);
  int   q0 = __shfl_xor(j0, 32), q1 = __shfl_xor(j1, 32), q2 = __shfl_xor(j2, 32);
  int   q3 = __shfl_xor(j3, 32), q4 = __shfl_xor(j4, 32), q5 = __shfl_xor(j5, 32);
  INS(m0, q0); INS(m1, q1); INS(m2, q2); INS(m3, q3); INS(m4, q4); INS(m5, q5);
#undef INS
  if (h == 0) {                                // single deterministic writer per (irow,s)
    size_t base = ((size_t)irow * NSPLIT + s) * 6;
    candj[base+0]=j0; candj[base+1]=j1; candj[base+2]=j2;
    candj[base+3]=j3; candj[base+4]=j4; candj[base+5]=j5;
  }
}

// ---------------- K3: exact fp32 anchors from candidates ----------------
__global__ __launch_bounds__(256) void anchor_kernel(const float* __restrict__ Xn,
                                                     const int* __restrict__ candj,
                                                     float* __restrict__ anchors) {
  __shared__ float xi[4][DIM];
  int wave = threadIdx.x >> 6, lane = threadIdx.x & 63;
  int row = blockIdx.x * 4 + wave;
  xi[wave][lane]      = Xn[(size_t)row * DIM + lane];
  xi[wave][lane + 64] = Xn[(size_t)row * DIM + lane + 64];
  __syncthreads();
  float d = 1e30f;
  if (lane < NC) {
    int idx = candj[(size_t)row * NC + lane];
    if (idx == row) d = 0.0f;                  // self: exactly 0, as reference
    else if (idx >= 0) {
      const float* xj = Xn + (size_t)idx * DIM;
      float acc = 0.f;
      for (int dd = 0; dd < DIM; dd += 4) {    // linear order = anchor/refine consistency
        float4 b = *(const float4*)(xj + dd);
        acc += xi[wave][dd+0] * b.x;
        acc += xi[wave][dd+1] * b.y;
        acc += xi[wave][dd+2] * b.z;
        acc += xi[wave][dd+3] * b.w;
      }
      d = 1.0f - acc;
    }
  }
  float m = 0.f;
  for (int t = 0; t < 4; ++t) {                // 4th smallest (K+1 incl self)
    float g = d;
#pragma unroll
    for (int off = 32; off > 0; off >>= 1) g = fminf(g, __shfl_xor(g, off));
    int kc = (d == g) ? lane : 0x7fffffff;
#pragma unroll
    for (int off = 32; off > 0; off >>= 1) kc = min(kc, __shfl_xor(kc, off));
    if (lane == kc) d = 1e30f;
    m = g;
  }
  if (lane == 0) anchors[row] = m;
}

// ---------------- K4: pass 2 — round-18 champion verbatim (100 us) ----------------
__global__ __launch_bounds__(512) void pass2_kernel(const ushort* __restrict__ Hi,
                                                    const float* __restrict__ anchors,
                                                    int* __restrict__ mcnt,
                                                    uint* __restrict__ ticket,
                                                    uint* __restrict__ flags) {
  __shared__ float4 BH[2][64 * 16];            // 32 KB double buffer, hi only
  __shared__ uint bl_buf[BLBUF];               // 4 KB borderline staging
  __shared__ uint bl_cnt, bl_base;
  int tid = threadIdx.x;
  int wave = tid >> 6, lane = tid & 63;        // wave 0..7: each owns 32 i-rows
  int col = lane & 31, h = lane >> 5;
  int ig = blockIdx.x >> 4, js = blockIdx.x & 15;   // grid 1024: 64 igs(256 rows) x 16 js
  int i0 = ig * 256;
  int irA = i0 + wave * 32 + col;
  float anchA = anchors[irA];
  float thrIn = 1.0f - anchA + MEPS, thrMid = 1.0f - anchA - MEPS;

  bf8v bA[8];
#pragma unroll
  for (int c = 0; c < 8; ++c)
    bA[c] = *(const bf8v*)(Hi + (size_t)irA * DIM + c * 16 + h * 8);
  if (tid == 0) bl_cnt = 0;

  int sl0, sl1, of0, of1;
  STADDR512(0, sl0, of0) STADDR512(1, sl1, of1)

  const int TBEG = js * 16, TEND = TBEG + 16;
  {                                            // prologue: stage first tile into buf0
    const char* hb = (const char*)Hi + (size_t)TBEG * 16384;
    BH[0][sl0] = *(const float4*)(hb + of0);
    BH[0][sl1] = *(const float4*)(hb + of1);
  }
  __syncthreads();
  int cur = 0;
  int cntI = 0;

  for (int t = TBEG; t < TEND; ++t) {
    int tp = (t + 1 < TEND) ? t + 1 : t;       // unconditional clamped prefetch (no spill)
    const char* hb = (const char*)Hi + (size_t)tp * 16384;
    float4 rh0 = *(const float4*)(hb + of0);
    float4 rh1 = *(const float4*)(hb + of1);
#pragma unroll
    for (int js2 = 0; js2 < 2; ++js2) {
      int jbase = t * 64 + js2 * 32;
      int lrow = js2 * 32 + col;
      int rswz = lrow & 15;
      const float4* B = BH[cur];
      bf8v ah[8];
#pragma unroll
      for (int c = 0; c < 8; ++c) ah[c] = ((const bf8v*)B)[lrow * 16 + ((c * 2 + h) ^ rswz)];
      f16v accA = {0,0,0,0,0,0,0,0,0,0,0,0,0,0,0,0};
#pragma unroll
      for (int c = 0; c < 8; ++c)
        accA = __builtin_amdgcn_mfma_f32_32x32x16_bf16(ah[c], bA[c], accA, 0, 0, 0);
      bool dodiag = (jbase + 32 > i0) && (jbase < i0 + 256);
      if (dodiag) {
#pragma unroll
        for (int r = 0; r < 16; ++r) {
          int jrow = (r & 3) + 8 * (r >> 2) + 4 * h;
          if (jbase + jrow == irA) accA[r] = 2.0f;  // self: definite in (c1=c2 -> not bl)
        }
      }
      uint blmask = 0;
#pragma unroll
      for (int r = 0; r < 16; ++r) {           // branchless: 2 cmp + add + shift-or
        float d = accA[r];
        int c1 = (d >= thrIn)  ? 1 : 0;
        int c2 = (d >= thrMid) ? 1 : 0;
        cntI += c1;
        blmask |= (uint)(c2 - c1) << r;        // borderline iff thrMid <= d < thrIn
      }
      // single ballot per subtile; rare lanes drain their borderline bits
      if (__ballot(blmask != 0)) {
        while (blmask) {
          int r = __ffs(blmask) - 1;
          blmask &= blmask - 1;
          int jrow = (r & 3) + 8 * (r >> 2) + 4 * h;
          uint pk = ((uint)irA << 14) | (uint)(jbase + jrow);
          uint s2 = atomicAdd(&bl_cnt, 1u);    // LDS atomic: ~2-3 per wave-subtile
          if (s2 < BLBUF) bl_buf[s2] = pk;
          else { uint tk = atomicAdd(ticket, 1u); if (tk < CAP) flags[tk] = pk; }
        }
      }
    }
    // write prefetched tile into the other buffer (vmcnt wait lands here, post-compute)
    BH[cur ^ 1][sl0] = rh0;
    BH[cur ^ 1][sl1] = rh1;
    __syncthreads();                           // single barrier per tile
    if (bl_cnt >= FLUSHTHR) {                  // uniform decision post-barrier (rare)
      uint n = bl_cnt; if (n > BLBUF) n = BLBUF;
      if (tid == 0) bl_base = atomicAdd(ticket, n);
      __syncthreads();
      uint b = bl_base;
      for (uint k = tid; k < n; k += 512)
        if (b + k < CAP) flags[b + k] = bl_buf[k];
      __syncthreads();
      if (tid == 0) bl_cnt = 0;
      __syncthreads();
    }
    cur ^= 1;
  }
  // final flush (appends visible: loop ended with barrier)
  {
    uint n = bl_cnt; if (n > BLBUF) n = BLBUF;
    if (tid == 0) bl_base = atomicAdd(ticket, n);
    __syncthreads();
    uint b = bl_base;
    for (uint k = tid; k < n; k += 512)
      if (b + k < CAP) flags[b + k] = bl_buf[k];
  }
  atomicAdd(&mcnt[irA], cntI);
}

// ---------------- K5: exact fp32 refinement of borderline pairs ----------------
__global__ __launch_bounds__(256) void refine_kernel(const float* __restrict__ Xn,
                                                     const float* __restrict__ anchors,
                                                     const uint* __restrict__ ticket,
                                                     const uint* __restrict__ flags,
                                                     int* __restrict__ mcnt) {
  uint n = *ticket; if (n > CAP) n = CAP;
  for (uint idx = blockIdx.x * 256 + threadIdx.x; idx < n; idx += gridDim.x * 256) {
    uint pk = flags[idx];
    int i = (int)(pk >> 14), j = (int)(pk & 16383u);
    const float* xi = Xn + (size_t)i * DIM;
    const float* xj = Xn + (size_t)j * DIM;
    float acc = 0.f;
    for (int d = 0; d < DIM; d += 4) {         // same linear order as anchor_kernel
      float4 a = *(const float4*)(xi + d);
      float4 b = *(const float4*)(xj + d);
      acc += a.x * b.x; acc += a.y * b.y; acc += a.z * b.z; acc += a.w * b.w;
    }
    float dist = 1.0f - acc;
    if (dist <= anchors[i]) atomicAdd(&mcnt[i], 1);
  }
}

// ---------------- K6a: parallel digamma partial sums (fixed-order tree) --------------
__device__ double digamma_d(double x) {
  double r = 0.0;
  while (x < 10.0) { r -= 1.0 / x; x += 1.0; }
  double inv = 1.0 / x, inv2 = inv * inv;
  double s = log(x) - 0.5 * inv;
  double p = inv2;
  s -= p * (1.0 / 12.0);
  p *= inv2; s += p * (1.0 / 120.0);
  p *= inv2; s -= p * (1.0 / 252.0);
  p *= inv2; s += p * (1.0 / 240.0);
  p *= inv2; s -= p * (1.0 / 132.0);
  return s + r;
}

__global__ __launch_bounds__(256) void digamma_part_kernel(const int* __restrict__ mcnt,
                                                           double* __restrict__ psum) {
  __shared__ double sm[256];
  int tid = threadIdx.x;
  int i = blockIdx.x * 256 + tid;
  sm[tid] = digamma_d((double)(mcnt[i] - 1));  // -1: self
  __syncthreads();
  for (int st = 128; st > 0; st >>= 1) {       // fixed-order tree: deterministic
    if (tid < st) sm[tid] += sm[tid + st];
    __syncthreads();
  }
  if (tid == 0) psum[blockIdx.x] = sm[0];
}

// ---------------- K6b: final scalar (fixed-order partial sum + hist terms) -----------
__global__ __launch_bounds__(256) void finalize_kernel(const double* __restrict__ psum,
                                                       const int* __restrict__ y,
                                                       float* __restrict__ out) {
  __shared__ int hist[NCLS];
  int tid = threadIdx.x;
  if (tid < NCLS) hist[tid] = 0;
  __syncthreads();
  for (int i = tid; i < NPTS; i += 256) atomicAdd(&hist[y[i]], 1);
  __syncthreads();
  if (tid == 0) {
    double s = 0.0;
    for (int b = 0; b < 64; ++b) s += psum[b]; // fixed serial order: deterministic
    double avg_m = s / (double)NPTS;
    double avg_N_x = 0.0;
    for (int c = 0; c < NCLS; ++c) {
      double cf = (double)hist[c];
      avg_N_x += (cf / (double)NPTS) * digamma_d(cf);
    }
    double mi = digamma_d((double)NPTS) - avg_N_x + digamma_d((double)KNN) - avg_m;
    out[0] = (float)(mi / log(2.0));
  }
}

// ---------------- launcher ----------------
extern "C" void kernel_launch(void* const* d_in, const int* in_sizes, int n_in,
                              void* d_out, int out_size, void* d_ws, size_t ws_size,
                              hipStream_t stream) {
  const float* X = (const float*)d_in[0];
  const int*   y = (const int*)d_in[1];
  float* out = (float*)d_out;
  char* ws = (char*)d_ws;

  float*  Xn      = (float*)(ws);                          // 8 MB
  ushort* Hi      = (ushort*)(ws + (8u  << 20));           // 4 MB
  ushort* Lo      = (ushort*)(ws + (12u << 20));           // 4 MB
  int*    candj   = (int*)(ws + (16u << 20));              // 16384*24*4 = 1.5 MB
  char*   p       = ws + (16u << 20) + (size_t)NPTS * NC * 4;
  int*    newpos  = (int*)(p);              p += (size_t)NPTS * 4;
  int*    y_new   = (int*)(p);              p += (size_t)NPTS * 4;
  int*    cls_st  = (int*)(p);              p += 256;
  float*  anchors = (float*)(p);            p += (size_t)NPTS * 4;
  int*    mcnt    = (int*)(p);              p += (size_t)NPTS * 4;
  uint*   ticket  = (uint*)(p);             p += 256;
  double* psum    = (double*)(p);           p += 64 * sizeof(double);
  uint*   flags   = (uint*)(p);                            // 6 MB (CAP)

  hipMemsetAsync(mcnt, 0, NPTS * sizeof(int), stream);
  hipMemsetAsync(ticket, 0, sizeof(uint), stream);

  sort_kernel<<<1, 256, 0, stream>>>(y, newpos, y_new, cls_st);
  prep_kernel<<<NPTS / 4, 256, 0, stream>>>(X, newpos, Xn, Hi, Lo);
  pass1_kernel<<<(NPTS / 128) * NSPLIT, 256, 0, stream>>>(Hi, Lo, y_new, cls_st, candj);
  anchor_kernel<<<NPTS / 4, 256, 0, stream>>>(Xn, candj, anchors);
  pass2_kernel<<<(NPTS / 256) * 16, 512, 0, stream>>>(Hi, anchors, mcnt, ticket, flags);
  refine_kernel<<<1024, 256, 0, stream>>>(Xn, anchors, ticket, flags, mcnt);
  digamma_part_kernel<<<NPTS / 256, 256, 0, stream>>>(mcnt, psum);
  finalize_kernel<<<1, 256, 0, stream>>>(psum, y, out);
}

// Round 20
// 300.624 us; speedup vs baseline: 1.1759x; 1.1759x over previous
//
#include <hip/hip_runtime.h>
#include <hip/hip_bf16.h>
#include <math.h>

#define NPTS 16384
#define DIM  128
#define NCLS 10
#define KNN  3
#define EPS  2.5e-5f      // 3-term screen bound (pass1 candidates; typical err ~1e-6)
#define MEPS 8.0e-3f      // hi-only screen bound: 2*2^-8 (bf16 7-bit mantissa) — near-tight
#define CAP  1572864      // borderline pair capacity (6 MB)
#define NSPLIT 4          // pass1 j-splits (champion config)
#define NC   24           // candidates per row = 4 splits * 6 (h-merged)
#define BLBUF 1024        // per-block LDS borderline buffer entries (4 KB)
#define FLUSHTHR 512      // flush when count exceeds this at a tile boundary

typedef float  f16v __attribute__((ext_vector_type(16)));
typedef __bf16 bf8v __attribute__((ext_vector_type(8)));

// staging address helpers: idx -> (lds slot, global byte offset within tile)
#define STADDR(k, SLOT, OFF) { int _i = tid + 256*(k); int _r = _i >> 4, _s = _i & 15; \
  SLOT = _r*16 + (_s ^ (_r & 15)); OFF = _r*256 + _s*16; }
#define STADDR512(k, SLOT, OFF) { int _i = tid + 512*(k); int _r = _i >> 4, _s = _i & 15; \
  SLOT = _r*16 + (_s ^ (_r & 15)); OFF = _r*256 + _s*16; }

// ---------------- K0: deterministic stable counting sort by class ----------------
__global__ __launch_bounds__(256) void sort_kernel(const int* __restrict__ y,
                                                   int* __restrict__ newpos,
                                                   int* __restrict__ y_new,
                                                   int* __restrict__ cls_start) {
  __shared__ int cnt[256 * NCLS];
  __shared__ int base[NCLS + 1];
  int t = threadIdx.x;
#pragma unroll
  for (int c = 0; c < NCLS; ++c) cnt[t * NCLS + c] = 0;
  for (int k = 0; k < 64; ++k) cnt[t * NCLS + y[t * 64 + k]]++;
  __syncthreads();
  if (t < NCLS) {
    int run = 0;
    for (int b = 0; b < 256; ++b) { int v = cnt[b * NCLS + t]; cnt[b * NCLS + t] = run; run += v; }
    base[t + 1] = run;
  }
  __syncthreads();
  if (t == 0) {
    base[0] = 0;
    for (int c = 1; c <= NCLS; ++c) base[c] += base[c - 1];
    for (int c = 0; c <= NCLS; ++c) cls_start[c] = base[c];
  }
  __syncthreads();
  for (int k = 0; k < 64; ++k) {
    int i = t * 64 + k;
    int c = y[i];
    int p = base[c] + cnt[t * NCLS + c]++;
    newpos[i] = p;
    y_new[p] = c;
  }
}

// ---------------- K1: normalize + bf16 hi/lo split, scattered to sorted order ----------
__global__ __launch_bounds__(256) void prep_kernel(const float* __restrict__ X,
                                                   const int* __restrict__ newpos,
                                                   float* __restrict__ Xn,
                                                   ushort* __restrict__ Hi,
                                                   ushort* __restrict__ Lo) {
  int row  = blockIdx.x * 4 + (threadIdx.x >> 6);
  int lane = threadIdx.x & 63;
  const float* xr = X + (size_t)row * DIM;
  float a = xr[lane], b = xr[lane + 64];
  float ss = a * a + b * b;
#pragma unroll
  for (int off = 32; off > 0; off >>= 1) ss += __shfl_xor(ss, off);
  float nrm = fmaxf(sqrtf(ss), 1e-8f);
  float an = a / nrm, bn = b / nrm;
  size_t np = (size_t)newpos[row];
  Xn[np * DIM + lane]      = an;
  Xn[np * DIM + lane + 64] = bn;
  __hip_bfloat16 ha = __float2bfloat16(an);
  __hip_bfloat16 hb = __float2bfloat16(bn);
  __hip_bfloat16 la = __float2bfloat16(an - __bfloat162float(ha));
  __hip_bfloat16 lb = __float2bfloat16(bn - __bfloat162float(hb));
  Hi[np * DIM + lane]      = *(ushort*)&ha;
  Hi[np * DIM + lane + 64] = *(ushort*)&hb;
  Lo[np * DIM + lane]      = *(ushort*)&la;
  Lo[np * DIM + lane + 64] = *(ushort*)&lb;
}

// ---------------- shared MFMA helper (identical dot path in both passes) -------------
__device__ __forceinline__ f16v tile_mfma(const float4* BH, const float4* BL,
                                          const bf8v bhi[8], const bf8v blo[8],
                                          int lrow, int h) {
  f16v acc = {0,0,0,0,0,0,0,0,0,0,0,0,0,0,0,0};
  int rswz = lrow & 15;
  bf8v ah[8], al[8];
#pragma unroll
  for (int c = 0; c < 8; ++c) ah[c] = ((const bf8v*)BH)[lrow * 16 + ((c * 2 + h) ^ rswz)];
#pragma unroll
  for (int c = 0; c < 8; ++c)
    acc = __builtin_amdgcn_mfma_f32_32x32x16_bf16(ah[c], bhi[c], acc, 0, 0, 0);
#pragma unroll
  for (int c = 0; c < 8; ++c) al[c] = ((const bf8v*)BL)[lrow * 16 + ((c * 2 + h) ^ rswz)];
#pragma unroll
  for (int c = 0; c < 8; ++c)
    acc = __builtin_amdgcn_mfma_f32_32x32x16_bf16(al[c], bhi[c], acc, 0, 0, 0);
#pragma unroll
  for (int c = 0; c < 8; ++c)
    acc = __builtin_amdgcn_mfma_f32_32x32x16_bf16(ah[c], blo[c], acc, 0, 0, 0);
  return acc;
}

// ---------------- K2: pass 1 — champion pipeline + class-filtered deferred mask ------
__global__ __launch_bounds__(256) void pass1_kernel(const ushort* __restrict__ Hi,
                                                    const ushort* __restrict__ Lo,
                                                    const int* __restrict__ y_new,
                                                    const int* __restrict__ cls_start,
                                                    int* __restrict__ candj) {
  __shared__ float4 BH[2][64 * 16];            // 32 KB double buffer (hi)
  __shared__ float4 BL[2][64 * 16];            // 32 KB double buffer (lo)
  int tid = threadIdx.x;
  int wave = tid >> 6, lane = tid & 63;
  int col = lane & 31, h = lane >> 5;
  int rb = blockIdx.x >> 2, s = blockIdx.x & 3;
  int irow = rb * 128 + wave * 32 + col;
  int myc = y_new[irow];
  int cs = cls_start[myc], ce = cls_start[myc + 1];
  int c_first = y_new[rb * 128];
  int c_last  = y_new[rb * 128 + 127];
  int jlo = cls_start[c_first], jhi = cls_start[c_last + 1];
  int T0 = jlo >> 6, T1 = (jhi + 63) >> 6;
  int TS0 = T0 + ((T1 - T0) * s) / NSPLIT;
  int TS1 = T0 + ((T1 - T0) * (s + 1)) / NSPLIT;

  bf8v bhi[8], blo[8];
#pragma unroll
  for (int c = 0; c < 8; ++c) {
    bhi[c] = *(const bf8v*)(Hi + (size_t)irow * DIM + c * 16 + h * 8);
    blo[c] = *(const bf8v*)(Lo + (size_t)irow * DIM + c * 16 + h * 8);
  }

  int sl0, sl1, sl2, sl3, of0, of1, of2, of3;
  STADDR(0, sl0, of0) STADDR(1, sl1, of1) STADDR(2, sl2, of2) STADDR(3, sl3, of3)

  float t0=-3e38f,t1=-3e38f,t2=-3e38f,t3=-3e38f,t4=-3e38f,t5=-3e38f;
  int   j0=-1,j1=-1,j2=-1,j3=-1,j4=-1,j5=-1;

#define INS(v, jj) do { float _pv = (v); int _pj = (jj); \
  if (_pv > t5) { t5 = _pv; j5 = _pj; \
    if (t5 > t4) { float _v=t4;t4=t5;t5=_v; int _j=j4;j4=j5;j5=_j; } \
    if (t4 > t3) { float _v=t3;t3=t4;t4=_v; int _j=j3;j3=j4;j4=_j; } \
    if (t3 > t2) { float _v=t2;t2=t3;t3=_v; int _j=j2;j2=j3;j3=_j; } \
    if (t2 > t1) { float _v=t1;t1=t2;t2=_v; int _j=j1;j1=j2;j2=_j; } \
    if (t1 > t0) { float _v=t0;t0=t1;t1=_v; int _j=j0;j0=j1;j1=_j; } } } while(0)

  {                                            // prologue: stage first tile into buf0
    const char* hb = (const char*)Hi + (size_t)TS0 * 16384;
    const char* lb = (const char*)Lo + (size_t)TS0 * 16384;
    BH[0][sl0] = *(const float4*)(hb + of0); BH[0][sl1] = *(const float4*)(hb + of1);
    BH[0][sl2] = *(const float4*)(hb + of2); BH[0][sl3] = *(const float4*)(hb + of3);
    BL[0][sl0] = *(const float4*)(lb + of0); BL[0][sl1] = *(const float4*)(lb + of1);
    BL[0][sl2] = *(const float4*)(lb + of2); BL[0][sl3] = *(const float4*)(lb + of3);
  }
  __syncthreads();
  int cur = 0;

  for (int t = TS0; t < TS1; ++t) {
    int tp = (t + 1 < TS1) ? t + 1 : t;        // unconditional clamped prefetch (no spill)
    const char* hb = (const char*)Hi + (size_t)tp * 16384;
    const char* lb = (const char*)Lo + (size_t)tp * 16384;
    float4 rh0 = *(const float4*)(hb + of0), rh1 = *(const float4*)(hb + of1);
    float4 rh2 = *(const float4*)(hb + of2), rh3 = *(const float4*)(hb + of3);
    float4 rl0 = *(const float4*)(lb + of0), rl1 = *(const float4*)(lb + of1);
    float4 rl2 = *(const float4*)(lb + of2), rl3 = *(const float4*)(lb + of3);
#pragma unroll
    for (int js2 = 0; js2 < 2; ++js2) {
      int jbase = t * 64 + js2 * 32;
      f16v acc = tile_mfma(BH[cur], BL[cur], bhi, blo, js2 * 32 + col, h);
      // dd is wave-uniform: this wave's 32 i-rows == this 32-j subtile
      bool dd = (irow >= jbase) && (irow < jbase + 32);
      if (__builtin_expect(dd, 0)) {           // rare: subtile containing self — full path
#pragma unroll
        for (int r = 0; r < 16; ++r) {
          int jrow = (r & 3) + 8 * (r >> 2) + 4 * h;
          int jg = jbase + jrow;
          float dot = acc[r];
          if (jg == irow) dot = 2.0f;          // self sentinel: guaranteed kept
          bool ok = (jg >= cs) && (jg < ce);
          if (ok) INS(dot, jg);
        }
      } else {
        // class-filtered deferred mask: per-subtile class window (~10 ops) +
        // 3 ops/elem dot gate; drain only for same-class elems beating stale t5.
        // Insert set identical: class exact, stale-t5 gate superset of current-t5,
        // drain ascending r = original order, INS rechecks current t5.
        int lo = cs - jbase, hi2 = ce - jbase;
        lo = lo < 0 ? 0 : lo;
        hi2 = hi2 > 32 ? 32 : hi2;
        uint clsm = 0;
        if (hi2 > lo) {                        // lo in [0,31], hi2 in (lo,32]
          uint mh = (hi2 >= 32) ? 0xFFFFFFFFu : ((1u << hi2) - 1u);
          uint rowm = mh & ~((1u << lo) - 1u);
          uint rm = rowm >> (4 * h);
          clsm = (rm & 0xFu) | ((rm >> 4) & 0xF0u) |
                 ((rm >> 8) & 0xF00u) | ((rm >> 12) & 0xF000u);
        }
        uint mask = 0;
#pragma unroll
        for (int r = 0; r < 16; ++r)
          mask |= (acc[r] > t5 ? 1u : 0u) << r;
        mask &= clsm;
        while (mask) {
          int r = __ffs(mask) - 1;
          mask &= mask - 1;
          int jrow = (r & 3) + 8 * (r >> 2) + 4 * h;
          int jg = jbase + jrow;
          INS(acc[r], jg);                     // class already verified by clsm
        }
      }
    }
    // write prefetched tile into the other buffer (vmcnt wait lands here, post-compute)
    BH[cur ^ 1][sl0] = rh0; BH[cur ^ 1][sl1] = rh1;
    BH[cur ^ 1][sl2] = rh2; BH[cur ^ 1][sl3] = rh3;
    BL[cur ^ 1][sl0] = rl0; BL[cur ^ 1][sl1] = rl1;
    BL[cur ^ 1][sl2] = rl2; BL[cur ^ 1][sl3] = rl3;
    __syncthreads();                           // single barrier per tile
    cur ^= 1;
  }

  // h-merge: exchange lists across lane^32 (same i-row, disjoint j-subsets)
  float m0 = __shfl_xor(t0, 32), m1 = __shfl_xor(t1, 32), m2 = __shfl_xor(t2, 32);
  float m3 = __shfl_xor(t3, 32), m4 = __shfl_xor(t4, 32), m5 = __shfl_xor(t5, 32);
  int   q0 = __shfl_xor(j0, 32), q1 = __shfl_xor(j1, 32), q2 = __shfl_xor(j2, 32);
  int   q3 = __shfl_xor(j3, 32), q4 = __shfl_xor(j4, 32), q5 = __shfl_xor(j5, 32);
  INS(m0, q0); INS(m1, q1); INS(m2, q2); INS(m3, q3); INS(m4, q4); INS(m5, q5);
#undef INS
  if (h == 0) {                                // single deterministic writer per (irow,s)
    size_t base = ((size_t)irow * NSPLIT + s) * 6;
    candj[base+0]=j0; candj[base+1]=j1; candj[base+2]=j2;
    candj[base+3]=j3; candj[base+4]=j4; candj[base+5]=j5;
  }
}

// ---------------- K3: exact fp32 anchors from candidates ----------------
__global__ __launch_bounds__(256) void anchor_kernel(const float* __restrict__ Xn,
                                                     const int* __restrict__ candj,
                                                     float* __restrict__ anchors) {
  __shared__ float xi[4][DIM];
  int wave = threadIdx.x >> 6, lane = threadIdx.x & 63;
  int row = blockIdx.x * 4 + wave;
  xi[wave][lane]      = Xn[(size_t)row * DIM + lane];
  xi[wave][lane + 64] = Xn[(size_t)row * DIM + lane + 64];
  __syncthreads();
  float d = 1e30f;
  if (lane < NC) {
    int idx = candj[(size_t)row * NC + lane];
    if (idx == row) d = 0.0f;                  // self: exactly 0, as reference
    else if (idx >= 0) {
      const float* xj = Xn + (size_t)idx * DIM;
      float acc = 0.f;
      for (int dd = 0; dd < DIM; dd += 4) {    // linear order = anchor/refine consistency
        float4 b = *(const float4*)(xj + dd);
        acc += xi[wave][dd+0] * b.x;
        acc += xi[wave][dd+1] * b.y;
        acc += xi[wave][dd+2] * b.z;
        acc += xi[wave][dd+3] * b.w;
      }
      d = 1.0f - acc;
    }
  }
  float m = 0.f;
  for (int t = 0; t < 4; ++t) {                // 4th smallest (K+1 incl self)
    float g = d;
#pragma unroll
    for (int off = 32; off > 0; off >>= 1) g = fminf(g, __shfl_xor(g, off));
    int kc = (d == g) ? lane : 0x7fffffff;
#pragma unroll
    for (int off = 32; off > 0; off >>= 1) kc = min(kc, __shfl_xor(kc, off));
    if (lane == kc) d = 1e30f;
    m = g;
  }
  if (lane == 0) anchors[row] = m;
}

// ---------------- K4: pass 2 — round-18 champion verbatim (100 us) ----------------
__global__ __launch_bounds__(512) void pass2_kernel(const ushort* __restrict__ Hi,
                                                    const float* __restrict__ anchors,
                                                    int* __restrict__ mcnt,
                                                    uint* __restrict__ ticket,
                                                    uint* __restrict__ flags) {
  __shared__ float4 BH[2][64 * 16];            // 32 KB double buffer, hi only
  __shared__ uint bl_buf[BLBUF];               // 4 KB borderline staging
  __shared__ uint bl_cnt, bl_base;
  int tid = threadIdx.x;
  int wave = tid >> 6, lane = tid & 63;        // wave 0..7: each owns 32 i-rows
  int col = lane & 31, h = lane >> 5;
  int ig = blockIdx.x >> 4, js = blockIdx.x & 15;   // grid 1024: 64 igs(256 rows) x 16 js
  int i0 = ig * 256;
  int irA = i0 + wave * 32 + col;
  float anchA = anchors[irA];
  float thrIn = 1.0f - anchA + MEPS, thrMid = 1.0f - anchA - MEPS;

  bf8v bA[8];
#pragma unroll
  for (int c = 0; c < 8; ++c)
    bA[c] = *(const bf8v*)(Hi + (size_t)irA * DIM + c * 16 + h * 8);
  if (tid == 0) bl_cnt = 0;

  int sl0, sl1, of0, of1;
  STADDR512(0, sl0, of0) STADDR512(1, sl1, of1)

  const int TBEG = js * 16, TEND = TBEG + 16;
  {                                            // prologue: stage first tile into buf0
    const char* hb = (const char*)Hi + (size_t)TBEG * 16384;
    BH[0][sl0] = *(const float4*)(hb + of0);
    BH[0][sl1] = *(const float4*)(hb + of1);
  }
  __syncthreads();
  int cur = 0;
  int cntI = 0;

  for (int t = TBEG; t < TEND; ++t) {
    int tp = (t + 1 < TEND) ? t + 1 : t;       // unconditional clamped prefetch (no spill)
    const char* hb = (const char*)Hi + (size_t)tp * 16384;
    float4 rh0 = *(const float4*)(hb + of0);
    float4 rh1 = *(const float4*)(hb + of1);
#pragma unroll
    for (int js2 = 0; js2 < 2; ++js2) {
      int jbase = t * 64 + js2 * 32;
      int lrow = js2 * 32 + col;
      int rswz = lrow & 15;
      const float4* B = BH[cur];
      bf8v ah[8];
#pragma unroll
      for (int c = 0; c < 8; ++c) ah[c] = ((const bf8v*)B)[lrow * 16 + ((c * 2 + h) ^ rswz)];
      f16v accA = {0,0,0,0,0,0,0,0,0,0,0,0,0,0,0,0};
#pragma unroll
      for (int c = 0; c < 8; ++c)
        accA = __builtin_amdgcn_mfma_f32_32x32x16_bf16(ah[c], bA[c], accA, 0, 0, 0);
      bool dodiag = (jbase + 32 > i0) && (jbase < i0 + 256);
      if (dodiag) {
#pragma unroll
        for (int r = 0; r < 16; ++r) {
          int jrow = (r & 3) + 8 * (r >> 2) + 4 * h;
          if (jbase + jrow == irA) accA[r] = 2.0f;  // self: definite in (c1=c2 -> not bl)
        }
      }
      uint blmask = 0;
#pragma unroll
      for (int r = 0; r < 16; ++r) {           // branchless: 2 cmp + add + shift-or
        float d = accA[r];
        int c1 = (d >= thrIn)  ? 1 : 0;
        int c2 = (d >= thrMid) ? 1 : 0;
        cntI += c1;
        blmask |= (uint)(c2 - c1) << r;        // borderline iff thrMid <= d < thrIn
      }
      // single ballot per subtile; rare lanes drain their borderline bits
      if (__ballot(blmask != 0)) {
        while (blmask) {
          int r = __ffs(blmask) - 1;
          blmask &= blmask - 1;
          int jrow = (r & 3) + 8 * (r >> 2) + 4 * h;
          uint pk = ((uint)irA << 14) | (uint)(jbase + jrow);
          uint s2 = atomicAdd(&bl_cnt, 1u);    // LDS atomic: ~2-3 per wave-subtile
          if (s2 < BLBUF) bl_buf[s2] = pk;
          else { uint tk = atomicAdd(ticket, 1u); if (tk < CAP) flags[tk] = pk; }
        }
      }
    }
    // write prefetched tile into the other buffer (vmcnt wait lands here, post-compute)
    BH[cur ^ 1][sl0] = rh0;
    BH[cur ^ 1][sl1] = rh1;
    __syncthreads();                           // single barrier per tile
    if (bl_cnt >= FLUSHTHR) {                  // uniform decision post-barrier (rare)
      uint n = bl_cnt; if (n > BLBUF) n = BLBUF;
      if (tid == 0) bl_base = atomicAdd(ticket, n);
      __syncthreads();
      uint b = bl_base;
      for (uint k = tid; k < n; k += 512)
        if (b + k < CAP) flags[b + k] = bl_buf[k];
      __syncthreads();
      if (tid == 0) bl_cnt = 0;
      __syncthreads();
    }
    cur ^= 1;
  }
  // final flush (appends visible: loop ended with barrier)
  {
    uint n = bl_cnt; if (n > BLBUF) n = BLBUF;
    if (tid == 0) bl_base = atomicAdd(ticket, n);
    __syncthreads();
    uint b = bl_base;
    for (uint k = tid; k < n; k += 512)
      if (b + k < CAP) flags[b + k] = bl_buf[k];
  }
  atomicAdd(&mcnt[irA], cntI);
}

// ---------------- K5: exact fp32 refinement of borderline pairs ----------------
__global__ __launch_bounds__(256) void refine_kernel(const float* __restrict__ Xn,
                                                     const float* __restrict__ anchors,
                                                     const uint* __restrict__ ticket,
                                                     const uint* __restrict__ flags,
                                                     int* __restrict__ mcnt) {
  uint n = *ticket; if (n > CAP) n = CAP;
  for (uint idx = blockIdx.x * 256 + threadIdx.x; idx < n; idx += gridDim.x * 256) {
    uint pk = flags[idx];
    int i = (int)(pk >> 14), j = (int)(pk & 16383u);
    const float* xi = Xn + (size_t)i * DIM;
    const float* xj = Xn + (size_t)j * DIM;
    float acc = 0.f;
    for (int d = 0; d < DIM; d += 4) {         // same linear order as anchor_kernel
      float4 a = *(const float4*)(xi + d);
      float4 b = *(const float4*)(xj + d);
      acc += a.x * b.x; acc += a.y * b.y; acc += a.z * b.z; acc += a.w * b.w;
    }
    float dist = 1.0f - acc;
    if (dist <= anchors[i]) atomicAdd(&mcnt[i], 1);
  }
}

// ---------------- K6a: parallel digamma partial sums (fixed-order tree) --------------
__device__ double digamma_d(double x) {
  double r = 0.0;
  while (x < 10.0) { r -= 1.0 / x; x += 1.0; }
  double inv = 1.0 / x, inv2 = inv * inv;
  double s = log(x) - 0.5 * inv;
  double p = inv2;
  s -= p * (1.0 / 12.0);
  p *= inv2; s += p * (1.0 / 120.0);
  p *= inv2; s -= p * (1.0 / 252.0);
  p *= inv2; s += p * (1.0 / 240.0);
  p *= inv2; s -= p * (1.0 / 132.0);
  return s + r;
}

__global__ __launch_bounds__(256) void digamma_part_kernel(const int* __restrict__ mcnt,
                                                           double* __restrict__ psum) {
  __shared__ double sm[256];
  int tid = threadIdx.x;
  int i = blockIdx.x * 256 + tid;
  sm[tid] = digamma_d((double)(mcnt[i] - 1));  // -1: self
  __syncthreads();
  for (int st = 128; st > 0; st >>= 1) {       // fixed-order tree: deterministic
    if (tid < st) sm[tid] += sm[tid + st];
    __syncthreads();
  }
  if (tid == 0) psum[blockIdx.x] = sm[0];
}

// ---------------- K6b: final scalar (fixed-order partial sum + hist terms) -----------
__global__ __launch_bounds__(256) void finalize_kernel(const double* __restrict__ psum,
                                                       const int* __restrict__ y,
                                                       float* __restrict__ out) {
  __shared__ int hist[NCLS];
  int tid = threadIdx.x;
  if (tid < NCLS) hist[tid] = 0;
  __syncthreads();
  for (int i = tid; i < NPTS; i += 256) atomicAdd(&hist[y[i]], 1);
  __syncthreads();
  if (tid == 0) {
    double s = 0.0;
    for (int b = 0; b < 64; ++b) s += psum[b]; // fixed serial order: deterministic
    double avg_m = s / (double)NPTS;
    double avg_N_x = 0.0;
    for (int c = 0; c < NCLS; ++c) {
      double cf = (double)hist[c];
      avg_N_x += (cf / (double)NPTS) * digamma_d(cf);
    }
    double mi = digamma_d((double)NPTS) - avg_N_x + digamma_d((double)KNN) - avg_m;
    out[0] = (float)(mi / log(2.0));
  }
}

// ---------------- launcher ----------------
extern "C" void kernel_launch(void* const* d_in, const int* in_sizes, int n_in,
                              void* d_out, int out_size, void* d_ws, size_t ws_size,
                              hipStream_t stream) {
  const float* X = (const float*)d_in[0];
  const int*   y = (const int*)d_in[1];
  float* out = (float*)d_out;
  char* ws = (char*)d_ws;

  float*  Xn      = (float*)(ws);                          // 8 MB
  ushort* Hi      = (ushort*)(ws + (8u  << 20));           // 4 MB
  ushort* Lo      = (ushort*)(ws + (12u << 20));           // 4 MB
  int*    candj   = (int*)(ws + (16u << 20));              // 16384*24*4 = 1.5 MB
  char*   p       = ws + (16u << 20) + (size_t)NPTS * NC * 4;
  int*    newpos  = (int*)(p);              p += (size_t)NPTS * 4;
  int*    y_new   = (int*)(p);              p += (size_t)NPTS * 4;
  int*    cls_st  = (int*)(p);              p += 256;
  float*  anchors = (float*)(p);            p += (size_t)NPTS * 4;
  int*    mcnt    = (int*)(p);              p += (size_t)NPTS * 4;
  uint*   ticket  = (uint*)(p);             p += 256;
  double* psum    = (double*)(p);           p += 64 * sizeof(double);
  uint*   flags   = (uint*)(p);                            // 6 MB (CAP)

  hipMemsetAsync(mcnt, 0, NPTS * sizeof(int), stream);
  hipMemsetAsync(ticket, 0, sizeof(uint), stream);

  sort_kernel<<<1, 256, 0, stream>>>(y, newpos, y_new, cls_st);
  prep_kernel<<<NPTS / 4, 256, 0, stream>>>(X, newpos, Xn, Hi, Lo);
  pass1_kernel<<<(NPTS / 128) * NSPLIT, 256, 0, stream>>>(Hi, Lo, y_new, cls_st, candj);
  anchor_kernel<<<NPTS / 4, 256, 0, stream>>>(Xn, candj, anchors);
  pass2_kernel<<<(NPTS / 256) * 16, 512, 0, stream>>>(Hi, anchors, mcnt, ticket, flags);
  refine_kernel<<<1024, 256, 0, stream>>>(Xn, anchors, ticket, flags, mcnt);
  digamma_part_kernel<<<NPTS / 256, 256, 0, stream>>>(mcnt, psum);
  finalize_kernel<<<1, 256, 0, stream>>>(psum, y, out);
}